// Round 1
// baseline (367.773 us; speedup 1.0000x reference)
//
#include <hip/hip_runtime.h>

#define NN 200000
#define DD 256
#define KK 20

// ---------------------------------------------------------------------------
// K1: main streaming pass. Grid = nb blocks x 512 threads.
// Block b owns rows [b*chunk, b*chunk+chunk). Thread t: column pair
// c2 = t&127 (columns 2*c2, 2*c2+1), row group r = t>>7 (wave-uniform).
// Produces per-block ztp partial [KK][DD] (flat 5120 floats) + term1 partial.
// ---------------------------------------------------------------------------
__global__ __launch_bounds__(512) void egac_main(
    const float* __restrict__ Z, const float* __restrict__ P,
    float* __restrict__ ztp_part, float* __restrict__ t1_part, int chunk) {
  const int t = threadIdx.x;
  const int c2 = t & 127;
  const int r = t >> 7;  // 0..3, uniform within each wave
  const int b = blockIdx.x;
  const int base = b * chunk;
  int rows = NN - base;
  if (rows > chunk) rows = chunk;

  float acc0[KK], acc1[KK];
#pragma unroll
  for (int k = 0; k < KK; ++k) { acc0[k] = 0.f; acc1[k] = 0.f; }
  float t1 = 0.f;

  const float2* Zb = (const float2*)(Z + (size_t)base * DD);

#pragma unroll 4
  for (int j = r; j < rows; j += 4) {
    float2 zv = Zb[j * (DD / 2) + c2];
    // row index is wave-uniform; readfirstlane lets the compiler scalarize
    // the P-row loads (s_load path -> SGPRs, low VGPR pressure).
    int rowu = __builtin_amdgcn_readfirstlane(base + j);
    const float4* pr = (const float4*)(P + (size_t)rowu * KK);
    float4 pa = pr[0], pb = pr[1], pc = pr[2], pd = pr[3], pe = pr[4];
    float pv[KK] = {pa.x, pa.y, pa.z, pa.w, pb.x, pb.y, pb.z, pb.w,
                    pc.x, pc.y, pc.z, pc.w, pd.x, pd.y, pd.z, pd.w,
                    pe.x, pe.y, pe.z, pe.w};
    t1 += zv.x * zv.x + zv.y * zv.y;
#pragma unroll
    for (int k = 0; k < KK; ++k) {
      acc0[k] += zv.x * pv[k];
      acc1[k] += zv.y * pv[k];
    }
  }

  // ---- intra-block reduction over the 4 r-groups ----
  __shared__ float red[KK][DD];  // [k][d], stride-1 in d -> 2-way alias, free
  __shared__ float wsum[8];
  for (int ph = 0; ph < 4; ++ph) {
    if (r == ph) {
      if (ph == 0) {
#pragma unroll
        for (int k = 0; k < KK; ++k) {
          red[k][2 * c2] = acc0[k];
          red[k][2 * c2 + 1] = acc1[k];
        }
      } else {
#pragma unroll
        for (int k = 0; k < KK; ++k) {
          red[k][2 * c2] += acc0[k];
          red[k][2 * c2 + 1] += acc1[k];
        }
      }
    }
    __syncthreads();
  }

  // term1: full-wave shuffle reduce, then 8 wave leaders -> LDS
#pragma unroll
  for (int off = 32; off > 0; off >>= 1) t1 += __shfl_xor(t1, off, 64);
  if ((t & 63) == 0) wsum[t >> 6] = t1;
  __syncthreads();

  // coalesced write-out of the 5120-float block partial
  const float* redf = &red[0][0];
#pragma unroll
  for (int i = 0; i < (KK * DD) / 512; ++i)
    ztp_part[(size_t)b * (KK * DD) + i * 512 + t] = redf[i * 512 + t];
  if (t == 0) {
    float s = 0.f;
#pragma unroll
    for (int w = 0; w < 8; ++w) s += wsum[w];
    t1_part[b] = s;
  }
}

// ---------------------------------------------------------------------------
// K2: cross-block reduction + final scalar. Grid = 160 blocks x 512 threads.
// Block handles 32 entries of the 5120-entry ztp; thread = (psub = t>>5,
// e_local = t&31); each thread sums 16 partials, LDS tree over 16 psubs,
// then sum of squares -> one atomicAdd per block. Block 0 adds term1.
// d_out must be zeroed before this kernel (hipMemsetAsync in kernel_launch).
// ---------------------------------------------------------------------------
__global__ __launch_bounds__(512) void egac_reduce(
    const float* __restrict__ ztp_part, const float* __restrict__ t1_part,
    float* __restrict__ out, int nb) {
  __shared__ float red[16][32];
  const int t = threadIdx.x;
  const int e_local = t & 31;
  const int psub = t >> 5;  // 0..15
  const int e = blockIdx.x * 32 + e_local;

  float s = 0.f;
#pragma unroll
  for (int j = 0; j < 16; ++j) {
    int p = psub * 16 + j;
    if (p < nb) s += ztp_part[(size_t)p * (KK * DD) + e];
  }
  red[psub][e_local] = s;
  __syncthreads();
  for (int sh = 8; sh >= 1; sh >>= 1) {
    if (psub < sh) red[psub][e_local] += red[psub + sh][e_local];
    __syncthreads();
  }
  if (t == 0) {
    float ssq = 0.f;
#pragma unroll
    for (int i = 0; i < 32; ++i) {
      float v = red[0][i];
      ssq += v * v;
    }
    atomicAdd(out, -ssq);  // term2 enters negatively
  }

  if (blockIdx.x == 0) {
    float v = (t < nb) ? t1_part[t] : 0.f;
#pragma unroll
    for (int off = 32; off > 0; off >>= 1) v += __shfl_xor(v, off, 64);
    __shared__ float w2[8];
    if ((t & 63) == 0) w2[t >> 6] = v;
    __syncthreads();
    if (t == 0) {
      float tt = 0.f;
#pragma unroll
      for (int w = 0; w < 8; ++w) tt += w2[w];
      atomicAdd(out, tt);  // + term1
    }
  }
}

extern "C" void kernel_launch(void* const* d_in, const int* in_sizes, int n_in,
                              void* d_out, int out_size, void* d_ws,
                              size_t ws_size, hipStream_t stream) {
  const float* Z = (const float*)d_in[0];
  const float* P = (const float*)d_in[1];
  float* out = (float*)d_out;

  int nb = 256;  // 1 block/CU; needs nb*(5120*4 + 4) = ~5.25 MB of ws
  size_t per_block = (size_t)KK * DD * sizeof(float) + sizeof(float);
  if (ws_size < (size_t)nb * per_block) {
    nb = (int)(ws_size / per_block);
    if (nb < 1) nb = 1;
  }
  float* ztp_part = (float*)d_ws;
  float* t1_part = (float*)d_ws + (size_t)nb * KK * DD;
  int chunk = (NN + nb - 1) / nb;

  hipMemsetAsync(d_out, 0, sizeof(float), stream);
  egac_main<<<nb, 512, 0, stream>>>(Z, P, ztp_part, t1_part, chunk);
  egac_reduce<<<160, 512, 0, stream>>>(ztp_part, t1_part, out, nb);
}

// Round 2
// 321.147 us; speedup vs baseline: 1.1452x; 1.1452x over previous
//
#include <hip/hip_runtime.h>

#define NN 200000
#define DD 256
#define KK 20

// ---------------------------------------------------------------------------
// K1: streaming pass. Grid = nb blocks x 256 threads (4 waves).
// Wave w of block b handles rows base + 4*s + w, s = 0..chunk/4-1.
// Each wave's 64 lanes cover the full 256-col row via float4 (lane -> cols
// 4*lane..4*lane+3). 80 fp32 accumulators/lane (20 k x 4 cols).
// Explicit 3-buffer software pipeline, prefetch distance 2: Z row (1KB/wave
// global_load_dwordx4) and P row (wave-uniform via readfirstlane -> scalar
// path) are loaded 2 stages ahead of use. __launch_bounds__(256,2) keeps
// the VGPR budget big enough (~170) that the pipeline lives in registers.
// ---------------------------------------------------------------------------

#define STAGE_LOAD(s, zv, Q0, Q1, Q2, Q3, Q4)                              \
  {                                                                        \
    int j_ = base + ((s) << 2) + w;                                        \
    if (j_ > NN - 1) j_ = 0; /* clamp: loaded data never consumed */       \
    zv = Zr[(size_t)j_ * (DD / 4) + lane];                                 \
    int ru_ = __builtin_amdgcn_readfirstlane(j_);                          \
    const float4* pp_ = (const float4*)(P + (size_t)ru_ * KK);             \
    Q0 = pp_[0]; Q1 = pp_[1]; Q2 = pp_[2]; Q3 = pp_[3]; Q4 = pp_[4];       \
  }

#define STAGE_COMPUTE(zv, Q0, Q1, Q2, Q3, Q4)                              \
  {                                                                        \
    float zz_[4] = {zv.x, zv.y, zv.z, zv.w};                               \
    float pv_[KK] = {Q0.x, Q0.y, Q0.z, Q0.w, Q1.x, Q1.y, Q1.z, Q1.w,       \
                     Q2.x, Q2.y, Q2.z, Q2.w, Q3.x, Q3.y, Q3.z, Q3.w,       \
                     Q4.x, Q4.y, Q4.z, Q4.w};                              \
    t1 += zz_[0] * zz_[0] + zz_[1] * zz_[1];                               \
    t1 += zz_[2] * zz_[2] + zz_[3] * zz_[3];                               \
    _Pragma("unroll") for (int k_ = 0; k_ < KK; ++k_) {                    \
      _Pragma("unroll") for (int c_ = 0; c_ < 4; ++c_)                     \
          acc[k_][c_] += zz_[c_] * pv_[k_];                                \
    }                                                                      \
  }

__global__ __launch_bounds__(256, 2) void egac_main(
    const float* __restrict__ Z, const float* __restrict__ P,
    float* __restrict__ ztp_part, float* __restrict__ t1_part, int chunk) {
  const int t = threadIdx.x;
  const int lane = t & 63;
  const int w = t >> 6;  // wave id 0..3 (wave-uniform)
  const int b = blockIdx.x;
  const int base = b * chunk;       // launcher guarantees nb*chunk == NN
  const int nst = chunk >> 2;       // stages per wave; (nst-2) % 3 == 0

  float acc[KK][4];
#pragma unroll
  for (int k = 0; k < KK; ++k)
#pragma unroll
    for (int c = 0; c < 4; ++c) acc[k][c] = 0.f;
  float t1 = 0.f;

  const float4* Zr = (const float4*)Z;

  float4 zA, A0, A1, A2, A3, A4;
  float4 zB, B0, B1, B2, B3, B4;
  float4 zC, C0, C1, C2, C3, C4;

  STAGE_LOAD(0, zA, A0, A1, A2, A3, A4);
  STAGE_LOAD(1, zB, B0, B1, B2, B3, B4);

  int s = 0;
  const int m_end = (nst - 2) / 3;
  for (int m = 0; m < m_end; ++m) {
    STAGE_LOAD(s + 2, zC, C0, C1, C2, C3, C4);
    STAGE_COMPUTE(zA, A0, A1, A2, A3, A4);
    STAGE_LOAD(s + 3, zA, A0, A1, A2, A3, A4);
    STAGE_COMPUTE(zB, B0, B1, B2, B3, B4);
    STAGE_LOAD(s + 4, zB, B0, B1, B2, B3, B4);
    STAGE_COMPUTE(zC, C0, C1, C2, C3, C4);
    s += 3;
  }
  STAGE_COMPUTE(zA, A0, A1, A2, A3, A4);
  STAGE_COMPUTE(zB, B0, B1, B2, B3, B4);

  // ---- intra-block reduction over the 4 waves ----
  __shared__ float red[KK][DD];
  __shared__ float wsum[4];
  for (int ph = 0; ph < 4; ++ph) {
    if (w == ph) {
      if (ph == 0) {
#pragma unroll
        for (int k = 0; k < KK; ++k)
          ((float4*)&red[k][0])[lane] =
              make_float4(acc[k][0], acc[k][1], acc[k][2], acc[k][3]);
      } else {
#pragma unroll
        for (int k = 0; k < KK; ++k) {
          float4 r = ((float4*)&red[k][0])[lane];
          r.x += acc[k][0]; r.y += acc[k][1];
          r.z += acc[k][2]; r.w += acc[k][3];
          ((float4*)&red[k][0])[lane] = r;
        }
      }
    }
    __syncthreads();
  }

  // term1: per-wave shuffle reduce, 4 wave leaders -> LDS
#pragma unroll
  for (int off = 32; off > 0; off >>= 1) t1 += __shfl_xor(t1, off, 64);
  if (lane == 0) wsum[w] = t1;
  __syncthreads();

  // coalesced float4 write-out of the 5120-float block partial
  float4* dst = (float4*)(ztp_part + (size_t)b * (KK * DD));
  const float4* src = (const float4*)&red[0][0];
#pragma unroll
  for (int i = 0; i < (KK * DD) / (4 * 256); ++i)
    dst[i * 256 + t] = src[i * 256 + t];
  if (t == 0) t1_part[b] = wsum[0] + wsum[1] + wsum[2] + wsum[3];
}

// ---------------------------------------------------------------------------
// K2: cross-block reduction + final scalar. Grid = 160 blocks x 512 threads.
// Block handles 32 entries of the 5120-entry ztp; thread = (psub = t>>5,
// e_local = t&31); thread sums partials p = psub, psub+16, ... (generic nb),
// LDS tree over 16 psubs, square-sum -> one atomicAdd per block.
// Block 0 also folds in term1. d_out zeroed via hipMemsetAsync first.
// ---------------------------------------------------------------------------
__global__ __launch_bounds__(512) void egac_reduce(
    const float* __restrict__ ztp_part, const float* __restrict__ t1_part,
    float* __restrict__ out, int nb) {
  __shared__ float red[16][32];
  const int t = threadIdx.x;
  const int el = t & 31;
  const int ps = t >> 5;  // 0..15
  const int e = blockIdx.x * 32 + el;

  float s = 0.f;
  for (int p = ps; p < nb; p += 16) s += ztp_part[(size_t)p * (KK * DD) + e];
  red[ps][el] = s;
  __syncthreads();
  for (int sh = 8; sh >= 1; sh >>= 1) {
    if (ps < sh) red[ps][el] += red[ps + sh][el];
    __syncthreads();
  }
  if (t == 0) {
    float ssq = 0.f;
#pragma unroll
    for (int i = 0; i < 32; ++i) {
      float v = red[0][i];
      ssq += v * v;
    }
    atomicAdd(out, -ssq);  // term2 enters negatively
  }

  if (blockIdx.x == 0) {
    float v = 0.f;
    for (int i = t; i < nb; i += 512) v += t1_part[i];
#pragma unroll
    for (int off = 32; off > 0; off >>= 1) v += __shfl_xor(v, off, 64);
    __shared__ float w2[8];
    if ((t & 63) == 0) w2[t >> 6] = v;
    __syncthreads();
    if (t == 0) {
      float tt = 0.f;
#pragma unroll
      for (int i = 0; i < 8; ++i) tt += w2[i];
      atomicAdd(out, tt);  // + term1
    }
  }
}

extern "C" void kernel_launch(void* const* d_in, const int* in_sizes, int n_in,
                              void* d_out, int out_size, void* d_ws,
                              size_t ws_size, hipStream_t stream) {
  const float* Z = (const float*)d_in[0];
  const float* P = (const float*)d_in[1];
  float* out = (float*)d_out;

  // nb * chunk == NN exactly; chunk/4 stages with (nst-2) % 3 == 0.
  // nb=1000 -> chunk=200 (nst=50); fallback nb=250 -> chunk=800 (nst=200).
  int nb = 1000;
  size_t need = (size_t)nb * (KK * DD) * sizeof(float) + (size_t)nb * sizeof(float);
  if (ws_size < need) nb = 250;
  int chunk = NN / nb;

  float* ztp_part = (float*)d_ws;
  float* t1_part = (float*)d_ws + (size_t)nb * KK * DD;

  hipMemsetAsync(d_out, 0, sizeof(float), stream);
  egac_main<<<nb, 256, 0, stream>>>(Z, P, ztp_part, t1_part, chunk);
  egac_reduce<<<160, 512, 0, stream>>>(ztp_part, t1_part, out, nb);
}